// Round 1
// baseline (2647.950 us; speedup 1.0000x reference)
//
#include <hip/hip_runtime.h>
#include <hip/hip_bf16.h>
#include <math.h>

#define T_TOK 65536      // B*N
#define C_DIM 1024
#define H_DIM 512        // C/2
#define Q_DIM 256        // C/4
#define MT 32            // tokens per block
#define SA_STRIDE 36     // 32 + 4 pad, 144B row (16B aligned)
#define SH_STRIDE 520    // 512 + 8 pad, 2080B row (16B aligned)

__device__ __forceinline__ float gelu_exact(float x) {
    return 0.5f * x * (1.0f + erff(x * 0.70710678118654752440f));
}

// bias2[n] = sum_j nf[j] * W_l1[512+j][n]   (token-invariant half of the concat GEMM)
__global__ void bias2_kernel(const float* __restrict__ nf,
                             const float* __restrict__ Wl1,
                             float* __restrict__ bias2) {
    int n = blockIdx.x * blockDim.x + threadIdx.x;  // 0..511
    if (n >= H_DIM) return;
    float s = 0.0f;
    for (int j = 0; j < H_DIM; ++j) {
        s = fmaf(nf[j], Wl1[(size_t)(H_DIM + j) * H_DIM + n], s);
    }
    bias2[n] = s;
}

__global__ __launch_bounds__(256)
void chanFSM_fused_kernel(const float* __restrict__ x,
                          const float* __restrict__ prev_m,
                          const float* __restrict__ gamma,
                          const float* __restrict__ beta,
                          const float* __restrict__ WL,    // [1024][512]
                          const float* __restrict__ Wl1,   // [1024][512] (use rows 0..511)
                          const float* __restrict__ Wl2,   // [512][256]
                          const float* __restrict__ w3,    // [256]
                          const float* __restrict__ bias2, // [512]
                          float* __restrict__ out,         // [T][C]
                          float* __restrict__ out_mask,    // [T]
                          float* __restrict__ out_curr) {  // [T]
    __shared__ float sA[MT][SA_STRIDE];
    __shared__ float sh[MT][SH_STRIDE];
    __shared__ float sMu[MT];
    __shared__ float sRs[MT];
    __shared__ float sw3[Q_DIM];
    __shared__ float sFlag[MT];

    const int tid = threadIdx.x;
    const int t0  = blockIdx.x * MT;
    const int wv  = tid >> 6;
    const int ln  = tid & 63;

    sw3[tid] = w3[tid];  // 256 threads == 256 elems

    // ---------- Phase 1: LayerNorm stats (8 tokens per wave) ----------
    for (int m = wv * 8; m < wv * 8 + 8; ++m) {
        const float* row = x + (size_t)(t0 + m) * C_DIM;
        double ds = 0.0, dsq = 0.0;
        #pragma unroll
        for (int j = 0; j < 16; ++j) {
            float v = row[ln + (j << 6)];
            ds  += (double)v;
            dsq += (double)v * (double)v;
        }
        #pragma unroll
        for (int off = 32; off > 0; off >>= 1) {
            ds  += __shfl_down(ds,  off);
            dsq += __shfl_down(dsq, off);
        }
        if (ln == 0) {
            double mu  = ds  * (1.0 / 1024.0);
            double var = dsq * (1.0 / 1024.0) - mu * mu;
            sMu[m] = (float)mu;
            sRs[m] = 1.0f / sqrtf((float)var + 1e-5f);
        }
    }

    // ---------- Phase 2: GEMM1  h1 = gelu(LN(x) @ W_L)  [32x512] ----------
    const int n0 = tid;
    const int n1 = tid + 256;
    float acc0[MT], acc1[MT];
    #pragma unroll
    for (int m = 0; m < MT; ++m) { acc0[m] = 0.0f; acc1[m] = 0.0f; }

    const int kk    = tid & 31;
    const int mbase = tid >> 5;

    for (int k0 = 0; k0 < C_DIM; k0 += 32) {
        __syncthreads();  // protect sA reads from previous iteration (and stats on iter 0)
        #pragma unroll
        for (int p = 0; p < 4; ++p) {
            int m = mbase + p * 8;
            float v = x[(size_t)(t0 + m) * C_DIM + k0 + kk];
            sA[m][kk] = fmaf((v - sMu[m]) * sRs[m], gamma[k0 + kk], beta[k0 + kk]);
        }
        __syncthreads();

        for (int k = 0; k < 32; k += 4) {
            const float* wr = WL + (size_t)(k0 + k) * H_DIM;
            float b00 = wr[n0],            b10 = wr[n1];
            float b01 = wr[H_DIM + n0],    b11 = wr[H_DIM + n1];
            float b02 = wr[2*H_DIM + n0],  b12 = wr[2*H_DIM + n1];
            float b03 = wr[3*H_DIM + n0],  b13 = wr[3*H_DIM + n1];
            #pragma unroll
            for (int m = 0; m < MT; ++m) {
                const float4 a = *(const float4*)&sA[m][k];
                acc0[m] = fmaf(a.x, b00, acc0[m]);
                acc0[m] = fmaf(a.y, b01, acc0[m]);
                acc0[m] = fmaf(a.z, b02, acc0[m]);
                acc0[m] = fmaf(a.w, b03, acc0[m]);
                acc1[m] = fmaf(a.x, b10, acc1[m]);
                acc1[m] = fmaf(a.y, b11, acc1[m]);
                acc1[m] = fmaf(a.z, b12, acc1[m]);
                acc1[m] = fmaf(a.w, b13, acc1[m]);
            }
        }
    }
    __syncthreads();  // sA dead; now write h1
    #pragma unroll
    for (int m = 0; m < MT; ++m) {
        sh[m][n0] = gelu_exact(acc0[m]);
        sh[m][n1] = gelu_exact(acc1[m]);
    }
    __syncthreads();

    // ---------- Phase 3: GEMM2  h2 = gelu(h1 @ W_l1_top + bias2)  [32x512] ----------
    {
        float bb0 = bias2[n0], bb1 = bias2[n1];
        #pragma unroll
        for (int m = 0; m < MT; ++m) { acc0[m] = bb0; acc1[m] = bb1; }
    }
    for (int k = 0; k < H_DIM; k += 4) {
        const float* wr = Wl1 + (size_t)k * H_DIM;
        float b00 = wr[n0],            b10 = wr[n1];
        float b01 = wr[H_DIM + n0],    b11 = wr[H_DIM + n1];
        float b02 = wr[2*H_DIM + n0],  b12 = wr[2*H_DIM + n1];
        float b03 = wr[3*H_DIM + n0],  b13 = wr[3*H_DIM + n1];
        #pragma unroll
        for (int m = 0; m < MT; ++m) {
            const float4 a = *(const float4*)&sh[m][k];
            acc0[m] = fmaf(a.x, b00, acc0[m]);
            acc0[m] = fmaf(a.y, b01, acc0[m]);
            acc0[m] = fmaf(a.z, b02, acc0[m]);
            acc0[m] = fmaf(a.w, b03, acc0[m]);
            acc1[m] = fmaf(a.x, b10, acc1[m]);
            acc1[m] = fmaf(a.y, b11, acc1[m]);
            acc1[m] = fmaf(a.z, b12, acc1[m]);
            acc1[m] = fmaf(a.w, b13, acc1[m]);
        }
    }
    __syncthreads();  // done reading h1
    #pragma unroll
    for (int m = 0; m < MT; ++m) {
        sh[m][n0] = gelu_exact(acc0[m]);
        sh[m][n1] = gelu_exact(acc1[m]);
    }
    __syncthreads();

    // ---------- Phase 4: GEMM3  h3 = gelu(h2 @ W_l2)  [32x256] ----------
    float acc3[MT];
    #pragma unroll
    for (int m = 0; m < MT; ++m) acc3[m] = 0.0f;
    for (int k = 0; k < H_DIM; k += 4) {
        const float* wr = Wl2 + (size_t)k * Q_DIM;
        float b0 = wr[tid];
        float b1 = wr[Q_DIM + tid];
        float b2 = wr[2*Q_DIM + tid];
        float b3 = wr[3*Q_DIM + tid];
        #pragma unroll
        for (int m = 0; m < MT; ++m) {
            const float4 a = *(const float4*)&sh[m][k];
            acc3[m] = fmaf(a.x, b0, acc3[m]);
            acc3[m] = fmaf(a.y, b1, acc3[m]);
            acc3[m] = fmaf(a.z, b2, acc3[m]);
            acc3[m] = fmaf(a.w, b3, acc3[m]);
        }
    }
    __syncthreads();  // done reading h2
    #pragma unroll
    for (int m = 0; m < MT; ++m) sh[m][tid] = gelu_exact(acc3[m]);
    __syncthreads();

    // ---------- Phase 5: GEMM4 + sigmoid + STE threshold ----------
    for (int m = wv * 8; m < wv * 8 + 8; ++m) {
        float z = 0.0f;
        #pragma unroll
        for (int j = 0; j < 4; ++j) {
            int k = ln + (j << 6);
            z = fmaf(sh[m][k], sw3[k], z);
        }
        #pragma unroll
        for (int off = 32; off > 0; off >>= 1) z += __shfl_down(z, off);
        if (ln == 0) {
            float prob = 1.0f / (1.0f + expf(-z));
            float t = prob * prev_m[t0 + m];
            float c = (t > 0.5f) ? 1.0f : 0.0f;
            sFlag[m] = c;
            out_mask[t0 + m] = c;                       // int mask, written as float
            out_curr[t0 + m] = (c > 0.0f) ? 1.0f : 1e-10f;  // curr_m + 1e-10 in fp32
        }
    }
    __syncthreads();

    // ---------- Phase 6: out = x * curr_m ----------
    const float4* x4 = (const float4*)(x   + (size_t)t0 * C_DIM);
    float4*       o4 = (float4*)      (out + (size_t)t0 * C_DIM);
    #pragma unroll 4
    for (int i = 0; i < 32; ++i) {
        int idx = tid + (i << 8);      // 0..8191
        int m = idx >> 8;              // 256 float4 per row
        float c = sFlag[m];
        float4 v = x4[idx];
        v.x *= c; v.y *= c; v.z *= c; v.w *= c;
        o4[idx] = v;
    }
}

extern "C" void kernel_launch(void* const* d_in, const int* in_sizes, int n_in,
                              void* d_out, int out_size, void* d_ws, size_t ws_size,
                              hipStream_t stream) {
    const float* x      = (const float*)d_in[0];  // [32,2048,1024]
    const float* nf     = (const float*)d_in[1];  // [512]
    const float* prev_m = (const float*)d_in[2];  // [65536]
    const float* gamma  = (const float*)d_in[3];  // [1024]
    const float* beta   = (const float*)d_in[4];  // [1024]
    const float* WL     = (const float*)d_in[5];  // [1024,512]
    const float* Wl1    = (const float*)d_in[6];  // [1024,512]
    const float* Wl2    = (const float*)d_in[7];  // [512,256]
    const float* w3     = (const float*)d_in[8];  // [256]

    float* out      = (float*)d_out;                       // [T, C]
    float* out_mask = out + (size_t)T_TOK * C_DIM;         // [T]
    float* out_curr = out_mask + T_TOK;                    // [T]

    float* bias2 = (float*)d_ws;  // 512 floats

    bias2_kernel<<<1, 512, 0, stream>>>(nf, Wl1, bias2);

    chanFSM_fused_kernel<<<T_TOK / MT, 256, 0, stream>>>(
        x, prev_m, gamma, beta, WL, Wl1, Wl2, w3, bias2,
        out, out_mask, out_curr);
}